// Round 13
// baseline (65.854 us; speedup 1.0000x reference)
//
#include <hip/hip_runtime.h>
#include <math.h>

#define N_NODES 30000
#define K_NBR   16
#define C_IN    256
#define C_OUT   128
#define KS      9
#define S_MB    17
#define BR      32

typedef __attribute__((ext_vector_type(4))) float f32x4;
typedef __attribute__((ext_vector_type(2))) float f32x2;
typedef __attribute__((ext_vector_type(8))) short bf16x8;

static __device__ __forceinline__ ushort f2bf(float f) {
    uint u = __builtin_bit_cast(uint, f);
    u += 0x7fffu + ((u >> 16) & 1u);          // round-to-nearest-even
    return (ushort)(u >> 16);
}

static __device__ __forceinline__ bf16x8 pack8(const f32x4 a, const f32x4 b) {
    bf16x8 r;
    r[0] = (short)f2bf(a.x); r[1] = (short)f2bf(a.y);
    r[2] = (short)f2bf(a.z); r[3] = (short)f2bf(a.w);
    r[4] = (short)f2bf(b.x); r[5] = (short)f2bf(b.y);
    r[6] = (short)f2bf(b.z); r[7] = (short)f2bf(b.w);
    return r;
}

// ---------------------------------------------------------------------------
// Fused MFMA GEMM (prep folded in — 2 dispatches total):
//   Gs[n][d] = Ws[d] * (ndata[n,:].W_lin[d,:])            (bf16, gathered)
//   Pc[n][d] = Gs + ndata[n,:].W_res[d,:] + Cd[d]         (bf16, per-node)
// Block: 512 threads = 8 waves, BR=32 rows x 256 stacked cols; wave w owns
// G cols w*16..+15 and the R cols of the SAME d -> in-register fold.
// B fragments converted f32->bf16 INLINE per kc from L2-resident W_lin/W_res
// (identical RNE rounding as the old prep kernel -> bit-identical results).
// Ws[c]/Cd[c] computed per-thread (each thread owns one channel c).
// A staged once in LDS, swizzle verified conflict-free (R7: 0 conflicts).
// ---------------------------------------------------------------------------
__global__ __launch_bounds__(512, 4)
void pcg_mfma(const float* __restrict__ ndata,
              const float* __restrict__ W_lin,
              const float* __restrict__ W_res,
              const float* __restrict__ weight,
              const float* __restrict__ b_lin,
              const float* __restrict__ bias,
              const float* __restrict__ b_res,
              ushort* __restrict__ Gs,
              ushort* __restrict__ Pc) {
    __shared__ short sA[8192];                 // 16 frags x 64 x 16B = 16 KB

    const int t  = threadIdx.x;
    const int n0 = blockIdx.x * BR;

    // ---- stage A tile: 2 x (two f32x4 -> one 16B ds_write_b128) ----
#pragma unroll
    for (int i = 0; i < 2; ++i) {
        const int v    = i * 512 + t;          // (row, kchunk) in 32 x 32
        const int row  = v >> 5;
        const int kch  = v & 31;
        f32x4 a0 = {0.f, 0.f, 0.f, 0.f}, a1 = {0.f, 0.f, 0.f, 0.f};
        if (n0 + row < N_NODES) {
            const float* p = &ndata[(size_t)(n0 + row) * C_IN + kch * 8];
            a0 = *reinterpret_cast<const f32x4*>(p);
            a1 = *reinterpret_cast<const f32x4*>(p + 4);
        }
        const int kc   = kch >> 2;
        const int ksub = kch & 3;
        const int f    = kc * 2 + (row >> 4);
        const int up   = (((row & 15) | (ksub << 4)) ^ ksub) ^ ((kc & 1) << 2);
        uint4 w;
        w.x = (uint)f2bf(a0.x) | ((uint)f2bf(a0.y) << 16);
        w.y = (uint)f2bf(a0.z) | ((uint)f2bf(a0.w) << 16);
        w.z = (uint)f2bf(a1.x) | ((uint)f2bf(a1.y) << 16);
        w.w = (uint)f2bf(a1.z) | ((uint)f2bf(a1.w) << 16);
        *reinterpret_cast<uint4*>(&sA[f * 512 + up * 8]) = w;
    }
    __syncthreads();

    const int wave = t >> 6;                   // 0..7
    const int l    = t & 63;
    const int bu   = l ^ (l >> 4);             // base swizzled 16B-unit index
    const int c    = wave * 16 + (l & 15);     // this thread's output channel
    const int krow = (l >> 4) * 8;             // fragment k-offset for lane

    const float* pG = &W_lin[(size_t)c * C_IN + krow];
    const float* pR = &W_res[(size_t)c * C_IN + krow];

    f32x4 acc[2][2] = {};                       // [rg][{G,R}]

#pragma unroll
    for (int kc = 0; kc < 8; ++kc) {
        // ---- B fragments: load f32 from L2, convert inline (same RNE) ----
        const bf16x8 bG = pack8(
            *reinterpret_cast<const f32x4*>(pG + kc * 32),
            *reinterpret_cast<const f32x4*>(pG + kc * 32 + 4));
        const bf16x8 bR = pack8(
            *reinterpret_cast<const f32x4*>(pR + kc * 32),
            *reinterpret_cast<const f32x4*>(pR + kc * 32 + 4));

        const int ux = bu ^ ((kc & 1) << 2);
        bf16x8 a[2];
#pragma unroll
        for (int rg = 0; rg < 2; ++rg)
            a[rg] = *reinterpret_cast<const bf16x8*>(
                        &sA[(kc * 2 + rg) * 512 + ux * 8]);
#pragma unroll
        for (int rg = 0; rg < 2; ++rg) {
            acc[rg][0] = __builtin_amdgcn_mfma_f32_16x16x32_bf16(
                             a[rg], bG, acc[rg][0], 0, 0, 0);
            acc[rg][1] = __builtin_amdgcn_mfma_f32_16x16x32_bf16(
                             a[rg], bR, acc[rg][1], 0, 0, 0);
        }
    }

    // ---- per-thread channel constants (same float-op order as old prep) ----
    float freq = powf(10000.0f, -(float)(c & ~1) / (float)C_OUT);
    float wsc = 0.f, pe = 0.f;
    for (int s = 0; s < S_MB; ++s) {
        int idx = (int)floorf((float)s * (9.0f / 17.0f));
        wsc += weight[c * KS + idx];
        float ang = (float)idx * freq;
        pe += (c & 1) ? cosf(ang) : sinf(ang);
    }
    const float cdc = wsc * ((float)(K_NBR + 1) * b_lin[c] + pe)
                      + bias[c] + b_res[c];

    // ---- epilogue: D layout col = lane&15, row = (lane>>4)*4 + reg ----
    const int rl = (l >> 4) * 4;
#pragma unroll
    for (int rg = 0; rg < 2; ++rg) {
#pragma unroll
        for (int j = 0; j < 4; ++j) {
            const int row = n0 + rg * 16 + rl + j;
            if (row < N_NODES) {
                const float gs = wsc * acc[rg][0][j];
                Gs[(size_t)row * C_OUT + c] = f2bf(gs);
                Pc[(size_t)row * C_OUT + c] = f2bf(gs + acc[rg][1][j] + cdc);
            }
        }
    }
}

// ---------------------------------------------------------------------------
// Gather: out[n][d] = Pc[n][d] + sum_k Gs[neighbors[n,k]][d]
// (R7 measured ~2.7 us — at its cache/write floor, unchanged)
// ---------------------------------------------------------------------------
__global__ __launch_bounds__(256)
void pcg_gather(const int* __restrict__ neighbors,
                const ushort* __restrict__ Gs,
                const ushort* __restrict__ Pc,
                float* __restrict__ out) {
    __shared__ int snb[64];
    const int t = threadIdx.x;
    if (t < 64) snb[t] = neighbors[(size_t)blockIdx.x * 64 + t];
    __syncthreads();

    const int g = t >> 6;                      // node group 0..3
    const int l = t & 63;
    const int n = blockIdx.x * 4 + g;

    uint p = *reinterpret_cast<const uint*>(&Pc[(size_t)n * C_OUT + 2 * l]);
    float a0 = __builtin_bit_cast(float, p << 16);
    float a1 = __builtin_bit_cast(float, p & 0xffff0000u);

#pragma unroll
    for (int k = 0; k < K_NBR; ++k) {
        const int m = snb[g * 16 + k];
        uint v = *reinterpret_cast<const uint*>(&Gs[(size_t)m * C_OUT + 2 * l]);
        a0 += __builtin_bit_cast(float, v << 16);
        a1 += __builtin_bit_cast(float, v & 0xffff0000u);
    }

    f32x2 o = {a0, a1};
    *reinterpret_cast<f32x2*>(&out[(size_t)n * C_OUT + 2 * l]) = o;
}

// ---------------------------------------------------------------------------
extern "C" void kernel_launch(void* const* d_in, const int* in_sizes, int n_in,
                              void* d_out, int out_size, void* d_ws, size_t ws_size,
                              hipStream_t stream) {
    const float* ndata     = (const float*)d_in[0];
    const int*   neighbors = (const int*)  d_in[1];
    const float* W_lin     = (const float*)d_in[2];
    const float* b_lin     = (const float*)d_in[3];
    const float* weight    = (const float*)d_in[4];
    const float* bias      = (const float*)d_in[5];
    const float* W_res     = (const float*)d_in[6];
    const float* b_res     = (const float*)d_in[7];
    float* out = (float*)d_out;

    ushort* Gq = (ushort*)d_ws;                          // Gs [N][128] = 7.68 MB
    ushort* Pq = Gq + (size_t)N_NODES * C_OUT;           // Pc [N][128] = 7.68 MB

    pcg_mfma<<<(N_NODES + BR - 1) / BR, 512, 0, stream>>>(
        ndata, W_lin, W_res, weight, b_lin, bias, b_res, Gq, Pq);
    pcg_gather<<<N_NODES / 4, 256, 0, stream>>>(neighbors, Gq, Pq, out);
}

// Round 14
// 60.469 us; speedup vs baseline: 1.0891x; 1.0891x over previous
//
#include <hip/hip_runtime.h>
#include <math.h>

#define N_NODES 30000
#define K_NBR   16
#define C_IN    256
#define C_OUT   128
#define KS      9
#define S_MB    17
#define BR      32

typedef __attribute__((ext_vector_type(4))) float  f32x4;
typedef __attribute__((ext_vector_type(2))) float  f32x2;
typedef __attribute__((ext_vector_type(8))) short  bf16x8;
typedef __attribute__((ext_vector_type(4))) uint   u32x4;

static __device__ __forceinline__ ushort f2bf(float f) {
    uint u = __builtin_bit_cast(uint, f);
    u += 0x7fffu + ((u >> 16) & 1u);          // round-to-nearest-even
    return (ushort)(u >> 16);
}

// HW packed f32->bf16 (RNE), 1 inst per 2 values — replaces ~8 VALU ops.
static __device__ __forceinline__ uint cvtpk(float a, float b) {
    uint r;
    asm("v_cvt_pk_bf16_f32 %0, %1, %2" : "=v"(r) : "v"(a), "v"(b));
    return r;
}

static __device__ __forceinline__ bf16x8 pack8(const f32x4 a, const f32x4 b) {
    u32x4 u;
    u.x = cvtpk(a.x, a.y); u.y = cvtpk(a.z, a.w);
    u.z = cvtpk(b.x, b.y); u.w = cvtpk(b.z, b.w);
    return __builtin_bit_cast(bf16x8, u);
}

// ---------------------------------------------------------------------------
// Fused MFMA GEMM (2 dispatches total):
//   Gs[n][d] = Ws[d] * (ndata[n,:].W_lin[d,:])            (bf16, gathered)
//   Pc[n][d] = Gs + ndata[n,:].W_res[d,:] + Cd[d]         (bf16, per-node)
// Block: 512 threads = 8 waves, BR=32 rows x 256 stacked cols; wave w owns
// G cols w*16..+15 and R cols of the SAME d -> in-register fold.
// R13 fixes: consts computed by 128 threads/block into LDS (not per-thread
// transcendentals — that cost ~25 us); all f32->bf16 via v_cvt_pk_bf16_f32.
// A staged once in LDS, swizzle conflict-free (R7: 0 conflicts).
// ---------------------------------------------------------------------------
__global__ __launch_bounds__(512, 4)
void pcg_mfma(const float* __restrict__ ndata,
              const float* __restrict__ W_lin,
              const float* __restrict__ W_res,
              const float* __restrict__ weight,
              const float* __restrict__ b_lin,
              const float* __restrict__ bias,
              const float* __restrict__ b_res,
              ushort* __restrict__ Gs,
              ushort* __restrict__ Pc) {
    __shared__ short sA[8192];                 // 16 frags x 64 x 16B = 16 KB
    __shared__ float sWs[C_OUT], sCd[C_OUT];

    const int t  = threadIdx.x;
    const int n0 = blockIdx.x * BR;

    // ---- stage A tile: 2 x (two f32x4 -> one 16B ds_write_b128) ----
#pragma unroll
    for (int i = 0; i < 2; ++i) {
        const int v    = i * 512 + t;          // (row, kchunk) in 32 x 32
        const int row  = v >> 5;
        const int kch  = v & 31;
        f32x4 a0 = {0.f, 0.f, 0.f, 0.f}, a1 = {0.f, 0.f, 0.f, 0.f};
        if (n0 + row < N_NODES) {
            const float* p = &ndata[(size_t)(n0 + row) * C_IN + kch * 8];
            a0 = *reinterpret_cast<const f32x4*>(p);
            a1 = *reinterpret_cast<const f32x4*>(p + 4);
        }
        const int kc   = kch >> 2;
        const int ksub = kch & 3;
        const int f    = kc * 2 + (row >> 4);
        const int up   = (((row & 15) | (ksub << 4)) ^ ksub) ^ ((kc & 1) << 2);
        u32x4 w;
        w.x = cvtpk(a0.x, a0.y);
        w.y = cvtpk(a0.z, a0.w);
        w.z = cvtpk(a1.x, a1.y);
        w.w = cvtpk(a1.z, a1.w);
        *reinterpret_cast<u32x4*>(&sA[f * 512 + up * 8]) = w;
    }

    // ---- per-channel consts: 128 threads, shared via LDS (same op order
    //      as the old prep kernel -> bit-identical values) ----
    if (t < C_OUT) {
        const int d = t;
        float freq = powf(10000.0f, -(float)(d & ~1) / (float)C_OUT);
        float ws = 0.f, pe = 0.f;
        for (int s = 0; s < S_MB; ++s) {
            int idx = (int)floorf((float)s * (9.0f / 17.0f));
            ws += weight[d * KS + idx];
            float ang = (float)idx * freq;
            pe += (d & 1) ? cosf(ang) : sinf(ang);
        }
        sWs[d] = ws;
        sCd[d] = ws * ((float)(K_NBR + 1) * b_lin[d] + pe)
                 + bias[d] + b_res[d];
    }
    __syncthreads();

    const int wave = t >> 6;                   // 0..7
    const int l    = t & 63;
    const int bu   = l ^ (l >> 4);             // base swizzled 16B-unit index
    const int c    = wave * 16 + (l & 15);     // this thread's output channel
    const int krow = (l >> 4) * 8;             // fragment k-offset for lane

    const float* pG = &W_lin[(size_t)c * C_IN + krow];
    const float* pR = &W_res[(size_t)c * C_IN + krow];

    f32x4 acc[2][2] = {};                       // [rg][{G,R}]

#pragma unroll
    for (int kc = 0; kc < 8; ++kc) {
        // ---- B fragments: f32 from L2, HW-packed convert ----
        const bf16x8 bG = pack8(
            *reinterpret_cast<const f32x4*>(pG + kc * 32),
            *reinterpret_cast<const f32x4*>(pG + kc * 32 + 4));
        const bf16x8 bR = pack8(
            *reinterpret_cast<const f32x4*>(pR + kc * 32),
            *reinterpret_cast<const f32x4*>(pR + kc * 32 + 4));

        const int ux = bu ^ ((kc & 1) << 2);
        bf16x8 a[2];
#pragma unroll
        for (int rg = 0; rg < 2; ++rg)
            a[rg] = *reinterpret_cast<const bf16x8*>(
                        &sA[(kc * 2 + rg) * 512 + ux * 8]);
#pragma unroll
        for (int rg = 0; rg < 2; ++rg) {
            acc[rg][0] = __builtin_amdgcn_mfma_f32_16x16x32_bf16(
                             a[rg], bG, acc[rg][0], 0, 0, 0);
            acc[rg][1] = __builtin_amdgcn_mfma_f32_16x16x32_bf16(
                             a[rg], bR, acc[rg][1], 0, 0, 0);
        }
    }

    // ---- epilogue: D layout col = lane&15, row = (lane>>4)*4 + reg ----
    const float wsc = sWs[c];
    const float cdc = sCd[c];
    const int rl = (l >> 4) * 4;
#pragma unroll
    for (int rg = 0; rg < 2; ++rg) {
#pragma unroll
        for (int j = 0; j < 4; ++j) {
            const int row = n0 + rg * 16 + rl + j;
            if (row < N_NODES) {
                const float gs = wsc * acc[rg][0][j];
                Gs[(size_t)row * C_OUT + c] = f2bf(gs);
                Pc[(size_t)row * C_OUT + c] = f2bf(gs + acc[rg][1][j] + cdc);
            }
        }
    }
}

// ---------------------------------------------------------------------------
// Gather: out[n][d] = Pc[n][d] + sum_k Gs[neighbors[n,k]][d]
// (R7 measured ~2.7 us — at its cache/write floor, unchanged)
// ---------------------------------------------------------------------------
__global__ __launch_bounds__(256)
void pcg_gather(const int* __restrict__ neighbors,
                const ushort* __restrict__ Gs,
                const ushort* __restrict__ Pc,
                float* __restrict__ out) {
    __shared__ int snb[64];
    const int t = threadIdx.x;
    if (t < 64) snb[t] = neighbors[(size_t)blockIdx.x * 64 + t];
    __syncthreads();

    const int g = t >> 6;                      // node group 0..3
    const int l = t & 63;
    const int n = blockIdx.x * 4 + g;

    uint p = *reinterpret_cast<const uint*>(&Pc[(size_t)n * C_OUT + 2 * l]);
    float a0 = __builtin_bit_cast(float, p << 16);
    float a1 = __builtin_bit_cast(float, p & 0xffff0000u);

#pragma unroll
    for (int k = 0; k < K_NBR; ++k) {
        const int m = snb[g * 16 + k];
        uint v = *reinterpret_cast<const uint*>(&Gs[(size_t)m * C_OUT + 2 * l]);
        a0 += __builtin_bit_cast(float, v << 16);
        a1 += __builtin_bit_cast(float, v & 0xffff0000u);
    }

    f32x2 o = {a0, a1};
    *reinterpret_cast<f32x2*>(&out[(size_t)n * C_OUT + 2 * l]) = o;
}

// ---------------------------------------------------------------------------
extern "C" void kernel_launch(void* const* d_in, const int* in_sizes, int n_in,
                              void* d_out, int out_size, void* d_ws, size_t ws_size,
                              hipStream_t stream) {
    const float* ndata     = (const float*)d_in[0];
    const int*   neighbors = (const int*)  d_in[1];
    const float* W_lin     = (const float*)d_in[2];
    const float* b_lin     = (const float*)d_in[3];
    const float* weight    = (const float*)d_in[4];
    const float* bias      = (const float*)d_in[5];
    const float* W_res     = (const float*)d_in[6];
    const float* b_res     = (const float*)d_in[7];
    float* out = (float*)d_out;

    ushort* Gq = (ushort*)d_ws;                          // Gs [N][128] = 7.68 MB
    ushort* Pq = Gq + (size_t)N_NODES * C_OUT;           // Pc [N][128] = 7.68 MB

    pcg_mfma<<<(N_NODES + BR - 1) / BR, 512, 0, stream>>>(
        ndata, W_lin, W_res, weight, b_lin, bias, b_res, Gq, Pq);
    pcg_gather<<<N_NODES / 4, 256, 0, stream>>>(neighbors, Gq, Pq, out);
}